// Round 13
// baseline (357.887 us; speedup 1.0000x reference)
//
#include <hip/hip_runtime.h>

// Problem constants (match reference setup_inputs)
#define NODES 50000
#define NEDGE 1600000
#define ND 64      // NODE_DIM
#define ED 32      // EDGE_DIM
#define HID 64     // HIDDEN
#define IN_DIM 96  // ND + ED

#define TW 16        // edges per wave-private micro-tile
#define MSG_LD 104   // bf16/row: 96+8 pad -> 208 B rows
#define H_LD   72    // bf16/row: 64+8 pad -> 144 B rows
#define W1_LD  104   // w1T row stride (bf16)
#define W2_LD  72    // w2T row stride (bf16)

typedef __bf16 bf16_t;
typedef __bf16 bf16x4_t __attribute__((ext_vector_type(4)));
typedef __bf16 bf16x8_t __attribute__((ext_vector_type(8)));
typedef float  f32x4_t  __attribute__((ext_vector_type(4)));

#define SCAN_B 256
#define SCAN_NBLK ((NODES + SCAN_B - 1) / SCAN_B)   // 196

#define NXCD 8
#define NODES_PER_G ((NODES + NXCD - 1) / NXCD)   // 6250

// ---------------- K0: zero out accumulator + counts ----------------
__global__ void zero_kernel(float* __restrict__ out, int* __restrict__ cnt) {
    int i = blockIdx.x * blockDim.x + threadIdx.x;
    int stride = gridDim.x * blockDim.x;
    const int total = NODES * ND;
    for (int idx = i; idx < total; idx += stride) out[idx] = 0.0f;
    for (int idx = i; idx < NODES; idx += stride) cnt[idx] = 0;
}

// ---------------- K1: histogram of dst ----------------
__global__ void hist_kernel(const int* __restrict__ ei, int* __restrict__ cnt) {
    int i = blockIdx.x * blockDim.x + threadIdx.x;
    int stride = gridDim.x * blockDim.x;
    for (int e = i; e < NEDGE; e += stride)
        atomicAdd(&cnt[ei[NEDGE + e]], 1);
}

// ---------------- K2a: per-block partial sums of cnt ----------------
__global__ void scan_sum_kernel(const int* __restrict__ cnt, int* __restrict__ bsum) {
    __shared__ int sh[SCAN_B];
    const int t = threadIdx.x, b = blockIdx.x;
    const int i = b * SCAN_B + t;
    sh[t] = (i < NODES) ? cnt[i] : 0;
    __syncthreads();
    for (int d = SCAN_B / 2; d > 0; d >>= 1) {
        if (t < d) sh[t] += sh[t + d];
        __syncthreads();
    }
    if (t == 0) bsum[b] = sh[0];
}

// ---------------- K2b: exclusive scan of 196 block sums (1 tiny block) ----------------
__global__ void scan_top_kernel(int* __restrict__ bsum) {
    __shared__ int sh[SCAN_B];
    const int t = threadIdx.x;
    sh[t] = (t < SCAN_NBLK) ? bsum[t] : 0;
    __syncthreads();
    for (int d = 1; d < SCAN_B; d <<= 1) {
        int v = (t >= d) ? sh[t - d] : 0;
        __syncthreads();
        sh[t] += v;
        __syncthreads();
    }
    if (t < SCAN_NBLK) bsum[t] = (t == 0) ? 0 : sh[t - 1];   // exclusive
}

// ---------------- K2c: fill cursor = global exclusive prefix of cnt ----------------
__global__ void scan_fill_kernel(const int* __restrict__ cnt, const int* __restrict__ bsum,
                                 int* __restrict__ cursor) {
    __shared__ int sh[SCAN_B];
    const int t = threadIdx.x, b = blockIdx.x;
    const int i = b * SCAN_B + t;
    int v = (i < NODES) ? cnt[i] : 0;
    sh[t] = v;
    __syncthreads();
    for (int d = 1; d < SCAN_B; d <<= 1) {
        int u = (t >= d) ? sh[t - d] : 0;
        __syncthreads();
        sh[t] += u;
        __syncthreads();
    }
    if (i < NODES) cursor[i] = bsum[b] + sh[t] - v;   // exclusive
}

// ---------------- K3: bucket-scatter, XCD-partitioned by dst range ----------------
__global__ void bucket_kernel(const int* __restrict__ ei, int* __restrict__ cursor,
                              int2* __restrict__ pd) {
    const int g   = blockIdx.x & (NXCD - 1);
    const int bg  = blockIdx.x >> 3;            // block index within group
    const int bpg = gridDim.x >> 3;             // blocks per group
    const int lo  = g * NODES_PER_G;
    const int hi  = min(lo + NODES_PER_G, NODES);
    int i = bg * blockDim.x + threadIdx.x;
    int stride = bpg * blockDim.x;
    for (int e = i; e < NEDGE; e += stride) {
        int d = ei[NEDGE + e];
        if (d >= lo && d < hi) {
            int pos = atomicAdd(&cursor[d], 1);
            pd[pos] = make_int2(e, d);
        }
    }
}

// ---------------- K4: per-edge MLP via bf16 MFMA — register prefetch + register scatter ----------------
// R12 structure, minus the m-LDS round trip and dstw LDS: GEMM2 output stays in
// registers; run-merge scatter via readlane(dst) + masked sums + shfl_xor butterfly.
__global__ __launch_bounds__(256, 4)
void edge_mlp_mfma(const float* __restrict__ x,
                   const float* __restrict__ edge_attr,
                   const float* __restrict__ W1, const float* __restrict__ b1,
                   const float* __restrict__ W2, const float* __restrict__ b2,
                   const int2* __restrict__ pd,
                   float* __restrict__ out_sum)
{
    __shared__ __align__(16) bf16_t w1T[HID * W1_LD];         // 13312 B
    __shared__ __align__(16) bf16_t w2T[ND * W2_LD];          //  9216 B
    __shared__ __align__(16) bf16_t msg_all[4 * TW * MSG_LD]; // 13312 B (total 35840)

    const int t    = threadIdx.x;
    const int lane = t & 63;
    const int w    = t >> 6;         // wave id 0..3
    const int col  = lane & 15;      // MFMA col / A-row selector
    const int kq   = lane >> 4;      // 0..3: k-quarter
    const int e    = lane >> 2;      // staging: edge row 0..15
    const int c    = lane & 3;       // staging: 4 lanes per row

    bf16_t* msg  = msg_all + w * TW * MSG_LD;   // [16][MSG_LD]
    bf16_t* hS   = msg;                          // [16][H_LD] overlay (h only)

    // ---- one-time: transpose W1,W2 into LDS (bf16) ----
    for (int i = t; i < IN_DIM * HID / 4; i += 256) {
        float4 v = ((const float4*)W1)[i];
        int k = i >> 4, j4 = (i & 15) * 4;      // W1[k][j4..j4+3]
        w1T[(j4 + 0) * W1_LD + k] = (bf16_t)v.x;
        w1T[(j4 + 1) * W1_LD + k] = (bf16_t)v.y;
        w1T[(j4 + 2) * W1_LD + k] = (bf16_t)v.z;
        w1T[(j4 + 3) * W1_LD + k] = (bf16_t)v.w;
    }
    for (int i = t; i < HID * ND / 4; i += 256) {
        float4 v = ((const float4*)W2)[i];
        int k = i >> 4, j4 = (i & 15) * 4;
        w2T[(j4 + 0) * W2_LD + k] = (bf16_t)v.x;
        w2T[(j4 + 1) * W2_LD + k] = (bf16_t)v.y;
        w2T[(j4 + 2) * W2_LD + k] = (bf16_t)v.z;
        w2T[(j4 + 3) * W2_LD + k] = (bf16_t)v.w;
    }
    float b1r[4], b2r[4];
    #pragma unroll
    for (int nt = 0; nt < 4; ++nt) {
        b1r[nt] = b1[col + 16 * nt];
        b2r[nt] = b2[col + 16 * nt];
    }
    __syncthreads();   // the only block barrier

    const int ntiles = NEDGE / TW;               // 100000
    const int wid = blockIdx.x * 4 + w;
    const int nw  = gridDim.x * 4;

    // ---- prefetch registers: this lane's share of one tile ----
    float4 xv0, xv1, xv2, xv3;   // x row chunks c, c+4, c+8, c+12
    float4 ev0, ev1;             // ea row chunks c*2, c*2+1
    int    dstv;                 // dst of edge eb + (lane&15)

    { // prologue: load first tile
        const int eb0 = wid * TW;
        int2 rec = pd[eb0 + e];
        dstv = pd[eb0 + col].y;
        const float4* xr = (const float4*)(x + (size_t)rec.y * ND);
        const float4* er = (const float4*)(edge_attr + (size_t)rec.x * ED);
        xv0 = xr[c]; xv1 = xr[c + 4]; xv2 = xr[c + 8]; xv3 = xr[c + 12];
        ev0 = er[c * 2]; ev1 = er[c * 2 + 1];
    }

    for (int tile = wid; tile < ntiles; tile += nw) {
        const int dcur = dstv;   // keep current tile's dsts before prefetch overwrites

        // ---- stage current registers into LDS (coalesced pattern) ----
        {
            bf16x4_t p;
            p[0] = (bf16_t)xv0.x; p[1] = (bf16_t)xv0.y; p[2] = (bf16_t)xv0.z; p[3] = (bf16_t)xv0.w;
            *(bf16x4_t*)&msg[e * MSG_LD + (c + 0) * 4] = p;
            p[0] = (bf16_t)xv1.x; p[1] = (bf16_t)xv1.y; p[2] = (bf16_t)xv1.z; p[3] = (bf16_t)xv1.w;
            *(bf16x4_t*)&msg[e * MSG_LD + (c + 4) * 4] = p;
            p[0] = (bf16_t)xv2.x; p[1] = (bf16_t)xv2.y; p[2] = (bf16_t)xv2.z; p[3] = (bf16_t)xv2.w;
            *(bf16x4_t*)&msg[e * MSG_LD + (c + 8) * 4] = p;
            p[0] = (bf16_t)xv3.x; p[1] = (bf16_t)xv3.y; p[2] = (bf16_t)xv3.z; p[3] = (bf16_t)xv3.w;
            *(bf16x4_t*)&msg[e * MSG_LD + (c + 12) * 4] = p;
            p[0] = (bf16_t)ev0.x; p[1] = (bf16_t)ev0.y; p[2] = (bf16_t)ev0.z; p[3] = (bf16_t)ev0.w;
            *(bf16x4_t*)&msg[e * MSG_LD + ND + (c * 2 + 0) * 4] = p;
            p[0] = (bf16_t)ev1.x; p[1] = (bf16_t)ev1.y; p[2] = (bf16_t)ev1.z; p[3] = (bf16_t)ev1.w;
            *(bf16x4_t*)&msg[e * MSG_LD + ND + (c * 2 + 1) * 4] = p;
        }

        // ---- issue next tile's loads (fly during GEMM+scatter below) ----
        if (tile + nw < ntiles) {
            const int eb1 = (tile + nw) * TW;
            int2 rec = pd[eb1 + e];
            dstv = pd[eb1 + col].y;
            const float4* xr = (const float4*)(x + (size_t)rec.y * ND);
            const float4* er = (const float4*)(edge_attr + (size_t)rec.x * ED);
            xv0 = xr[c]; xv1 = xr[c + 4]; xv2 = xr[c + 8]; xv3 = xr[c + 12];
            ev0 = er[c * 2]; ev1 = er[c * 2 + 1];
        }

        // ---- GEMM1: h[0..15][0..63] = relu(msg @ W1 + b1) ----
        const int ab = col * MSG_LD + kq * 8;
        bf16x8_t af0 = *(const bf16x8_t*)&msg[ab + 0 * 32];
        bf16x8_t af1 = *(const bf16x8_t*)&msg[ab + 1 * 32];
        bf16x8_t af2 = *(const bf16x8_t*)&msg[ab + 2 * 32];
        f32x4_t acc[4];
        #pragma unroll
        for (int nt = 0; nt < 4; ++nt) {
            const bf16_t* wrow = &w1T[(col + 16 * nt) * W1_LD + kq * 8];
            bf16x8_t f0 = *(const bf16x8_t*)(wrow + 0 * 32);
            bf16x8_t f1 = *(const bf16x8_t*)(wrow + 1 * 32);
            bf16x8_t f2 = *(const bf16x8_t*)(wrow + 2 * 32);
            acc[nt] = (f32x4_t){0.0f, 0.0f, 0.0f, 0.0f};
            acc[nt] = __builtin_amdgcn_mfma_f32_16x16x32_bf16(af0, f0, acc[nt], 0, 0, 0);
            acc[nt] = __builtin_amdgcn_mfma_f32_16x16x32_bf16(af1, f1, acc[nt], 0, 0, 0);
            acc[nt] = __builtin_amdgcn_mfma_f32_16x16x32_bf16(af2, f2, acc[nt], 0, 0, 0);
        }
        // epilogue: bias+relu -> hS (C/D: row = 4*kq + r, col = col + 16*nt)
        #pragma unroll
        for (int nt = 0; nt < 4; ++nt)
            #pragma unroll
            for (int r = 0; r < 4; ++r)
                hS[(4 * kq + r) * H_LD + col + 16 * nt] =
                    (bf16_t)fmaxf(acc[nt][r] + b1r[nt], 0.0f);

        // ---- GEMM2: m = relu(h @ W2 + b2) — output stays in registers ----
        const int hb = col * H_LD + kq * 8;
        bf16x8_t ah0 = *(const bf16x8_t*)&hS[hb + 0 * 32];
        bf16x8_t ah1 = *(const bf16x8_t*)&hS[hb + 1 * 32];
        f32x4_t acc2[4];
        #pragma unroll
        for (int nt = 0; nt < 4; ++nt) {
            const bf16_t* wrow = &w2T[(col + 16 * nt) * W2_LD + kq * 8];
            bf16x8_t f0 = *(const bf16x8_t*)(wrow + 0 * 32);
            bf16x8_t f1 = *(const bf16x8_t*)(wrow + 1 * 32);
            acc2[nt] = (f32x4_t){0.0f, 0.0f, 0.0f, 0.0f};
            acc2[nt] = __builtin_amdgcn_mfma_f32_16x16x32_bf16(ah0, f0, acc2[nt], 0, 0, 0);
            acc2[nt] = __builtin_amdgcn_mfma_f32_16x16x32_bf16(ah1, f1, acc2[nt], 0, 0, 0);
        }
        // m values in registers: mv[nt][r] = m[4kq+r][col+16nt]
        float mv0[4], mv1[4], mv2[4], mv3[4];
        #pragma unroll
        for (int r = 0; r < 4; ++r) {
            mv0[r] = fmaxf(acc2[0][r] + b2r[0], 0.0f);
            mv1[r] = fmaxf(acc2[1][r] + b2r[1], 0.0f);
            mv2[r] = fmaxf(acc2[2][r] + b2r[2], 0.0f);
            mv3[r] = fmaxf(acc2[3][r] + b2r[3], 0.0f);
        }

        // ---- register run-merge scatter over 16 sorted rows ----
        // runs found via wave-uniform readlane on dcur; per run: masked per-lane
        // sums + shfl_xor(16,32) butterfly over kq groups; lane (col+16kq) = out col.
        {
            int r0 = 0;
            while (r0 < TW) {
                const int d = __builtin_amdgcn_readlane(dcur, r0);
                int r1 = r0 + 1;
                while (r1 < TW && __builtin_amdgcn_readlane(dcur, r1) == d) ++r1;

                float s0 = 0.0f, s1 = 0.0f, s2 = 0.0f, s3 = 0.0f;
                #pragma unroll
                for (int r = 0; r < 4; ++r) {
                    const int row = 4 * kq + r;
                    const bool in = (row >= r0) && (row < r1);
                    s0 += in ? mv0[r] : 0.0f;
                    s1 += in ? mv1[r] : 0.0f;
                    s2 += in ? mv2[r] : 0.0f;
                    s3 += in ? mv3[r] : 0.0f;
                }
                s0 += __shfl_xor(s0, 16); s0 += __shfl_xor(s0, 32);
                s1 += __shfl_xor(s1, 16); s1 += __shfl_xor(s1, 32);
                s2 += __shfl_xor(s2, 16); s2 += __shfl_xor(s2, 32);
                s3 += __shfl_xor(s3, 16); s3 += __shfl_xor(s3, 32);
                const float sv = (kq == 0) ? s0 : (kq == 1) ? s1 : (kq == 2) ? s2 : s3;
                atomicAdd(&out_sum[(size_t)d * ND + lane], sv);
                r0 = r1;
            }
        }
    }
}

// ---------------- K5: finalize out = sum/max(cnt,1) + x ----------------
__global__ void finalize_kernel(const float* __restrict__ x,
                                const int* __restrict__ cnt,
                                float* __restrict__ out)
{
    int i = blockIdx.x * blockDim.x + threadIdx.x;
    int stride = gridDim.x * blockDim.x;
    const int total4 = NODES * ND / 4;
    for (int idx = i; idx < total4; idx += stride) {
        const int n = idx / (ND / 4);
        const float inv = 1.0f / fmaxf((float)cnt[n], 1.0f);
        float4 s = ((const float4*)out)[idx];
        float4 xv = ((const float4*)x)[idx];
        float4 r;
        r.x = s.x * inv + xv.x;
        r.y = s.y * inv + xv.y;
        r.z = s.z * inv + xv.z;
        r.w = s.w * inv + xv.w;
        ((float4*)out)[idx] = r;
    }
}

extern "C" void kernel_launch(void* const* d_in, const int* in_sizes, int n_in,
                              void* d_out, int out_size, void* d_ws, size_t ws_size,
                              hipStream_t stream) {
    const float* x  = (const float*)d_in[0];
    const int*   ei = (const int*)d_in[1];     // int64 in reference -> int32 on device
    const float* ea = (const float*)d_in[2];
    const float* W1 = (const float*)d_in[3];
    const float* b1 = (const float*)d_in[4];
    const float* W2 = (const float*)d_in[5];
    const float* b2 = (const float*)d_in[6];
    float* out = (float*)d_out;

    // d_ws layout (ints): cnt[N] | cursor[N] | pd[2E] | bsum[256]
    int*  cnt    = (int*)d_ws;
    int*  cursor = cnt + NODES;
    int2* pd     = (int2*)(cursor + NODES);
    int*  bsum   = (int*)(pd + NEDGE);

    hipLaunchKernelGGL(zero_kernel, dim3(2048), dim3(256), 0, stream, out, cnt);
    hipLaunchKernelGGL(hist_kernel, dim3(2048), dim3(256), 0, stream, ei, cnt);
    hipLaunchKernelGGL(scan_sum_kernel, dim3(SCAN_NBLK), dim3(SCAN_B), 0, stream, cnt, bsum);
    hipLaunchKernelGGL(scan_top_kernel, dim3(1), dim3(SCAN_B), 0, stream, bsum);
    hipLaunchKernelGGL(scan_fill_kernel, dim3(SCAN_NBLK), dim3(SCAN_B), 0, stream, cnt, bsum, cursor);
    hipLaunchKernelGGL(bucket_kernel, dim3(2048), dim3(256), 0, stream, ei, cursor, pd);
    hipLaunchKernelGGL(edge_mlp_mfma, dim3(1024), dim3(256), 0, stream,
                       x, ea, W1, b1, W2, b2, pd, out);
    hipLaunchKernelGGL(finalize_kernel, dim3(1600), dim3(256), 0, stream, x, cnt, out);
}

// Round 14
// 234.358 us; speedup vs baseline: 1.5271x; 1.5271x over previous
//
#include <hip/hip_runtime.h>

// Problem constants (match reference setup_inputs)
#define NODES 50000
#define NEDGE 1600000
#define ND 64      // NODE_DIM
#define ED 32      // EDGE_DIM
#define HID 64     // HIDDEN
#define IN_DIM 96  // ND + ED

#define TW 16        // edges per wave-private micro-tile
#define MSG_LD 104   // bf16/row: 96+8 pad -> 208 B rows
#define H_LD   72    // bf16/row: 64+8 pad -> 144 B rows (h overlays msg)
#define MT_LD  24    // mT row stride (bf16): 48 B rows, b128-aligned, low-conflict
#define W1_LD  104   // w1T row stride (bf16)
#define W2_LD  72    // w2T row stride (bf16)

typedef __bf16 bf16_t;
typedef __bf16 bf16x4_t __attribute__((ext_vector_type(4)));
typedef __bf16 bf16x8_t __attribute__((ext_vector_type(8)));
typedef float  f32x4_t  __attribute__((ext_vector_type(4)));

#define SCAN_B 256
#define SCAN_NBLK ((NODES + SCAN_B - 1) / SCAN_B)   // 196

#define NXCD 8
#define NODES_PER_G ((NODES + NXCD - 1) / NXCD)   // 6250

// ---------------- K0: zero out accumulator + counts ----------------
__global__ void zero_kernel(float* __restrict__ out, int* __restrict__ cnt) {
    int i = blockIdx.x * blockDim.x + threadIdx.x;
    int stride = gridDim.x * blockDim.x;
    const int total = NODES * ND;
    for (int idx = i; idx < total; idx += stride) out[idx] = 0.0f;
    for (int idx = i; idx < NODES; idx += stride) cnt[idx] = 0;
}

// ---------------- K1: histogram of dst ----------------
__global__ void hist_kernel(const int* __restrict__ ei, int* __restrict__ cnt) {
    int i = blockIdx.x * blockDim.x + threadIdx.x;
    int stride = gridDim.x * blockDim.x;
    for (int e = i; e < NEDGE; e += stride)
        atomicAdd(&cnt[ei[NEDGE + e]], 1);
}

// ---------------- K2a: per-block partial sums of cnt ----------------
__global__ void scan_sum_kernel(const int* __restrict__ cnt, int* __restrict__ bsum) {
    __shared__ int sh[SCAN_B];
    const int t = threadIdx.x, b = blockIdx.x;
    const int i = b * SCAN_B + t;
    sh[t] = (i < NODES) ? cnt[i] : 0;
    __syncthreads();
    for (int d = SCAN_B / 2; d > 0; d >>= 1) {
        if (t < d) sh[t] += sh[t + d];
        __syncthreads();
    }
    if (t == 0) bsum[b] = sh[0];
}

// ---------------- K2b: exclusive scan of 196 block sums (1 tiny block) ----------------
__global__ void scan_top_kernel(int* __restrict__ bsum) {
    __shared__ int sh[SCAN_B];
    const int t = threadIdx.x;
    sh[t] = (t < SCAN_NBLK) ? bsum[t] : 0;
    __syncthreads();
    for (int d = 1; d < SCAN_B; d <<= 1) {
        int v = (t >= d) ? sh[t - d] : 0;
        __syncthreads();
        sh[t] += v;
        __syncthreads();
    }
    if (t < SCAN_NBLK) bsum[t] = (t == 0) ? 0 : sh[t - 1];   // exclusive
}

// ---------------- K2c: fill cursor = global exclusive prefix of cnt ----------------
__global__ void scan_fill_kernel(const int* __restrict__ cnt, const int* __restrict__ bsum,
                                 int* __restrict__ cursor) {
    __shared__ int sh[SCAN_B];
    const int t = threadIdx.x, b = blockIdx.x;
    const int i = b * SCAN_B + t;
    int v = (i < NODES) ? cnt[i] : 0;
    sh[t] = v;
    __syncthreads();
    for (int d = 1; d < SCAN_B; d <<= 1) {
        int u = (t >= d) ? sh[t - d] : 0;
        __syncthreads();
        sh[t] += u;
        __syncthreads();
    }
    if (i < NODES) cursor[i] = bsum[b] + sh[t] - v;   // exclusive
}

// ---------------- K3: bucket-scatter, XCD-partitioned by dst range ----------------
__global__ void bucket_kernel(const int* __restrict__ ei, int* __restrict__ cursor,
                              int2* __restrict__ pd) {
    const int g   = blockIdx.x & (NXCD - 1);
    const int bg  = blockIdx.x >> 3;            // block index within group
    const int bpg = gridDim.x >> 3;             // blocks per group
    const int lo  = g * NODES_PER_G;
    const int hi  = min(lo + NODES_PER_G, NODES);
    int i = bg * blockDim.x + threadIdx.x;
    int stride = bpg * blockDim.x;
    for (int e = i; e < NEDGE; e += stride) {
        int d = ei[NEDGE + e];
        if (d >= lo && d < hi) {
            int pos = atomicAdd(&cursor[d], 1);
            pd[pos] = make_int2(e, d);
        }
    }
}

// ---------------- K4: per-edge MLP via bf16 MFMA — prefetch + transposed-m scatter ----------------
// R12 structure. Changes: m written transposed (mT[64][24] overlaying msg) so the
// scatter reads are 2x ds_read_b128/lane; dsts kept in a register (readlane with
// compile-time index in a fixed unrolled 16-iter merge) -> dstw LDS deleted.
__global__ __launch_bounds__(256, 4)
void edge_mlp_mfma(const float* __restrict__ x,
                   const float* __restrict__ edge_attr,
                   const float* __restrict__ W1, const float* __restrict__ b1,
                   const float* __restrict__ W2, const float* __restrict__ b2,
                   const int2* __restrict__ pd,
                   float* __restrict__ out_sum)
{
    __shared__ __align__(16) bf16_t w1T[HID * W1_LD];         // 13312 B
    __shared__ __align__(16) bf16_t w2T[ND * W2_LD];          //  9216 B
    __shared__ __align__(16) bf16_t msg_all[4 * TW * MSG_LD]; // 13312 B (total 35840)

    const int t    = threadIdx.x;
    const int lane = t & 63;
    const int w    = t >> 6;         // wave id 0..3
    const int col  = lane & 15;      // MFMA col / A-row selector
    const int kq   = lane >> 4;      // 0..3: k-quarter
    const int e    = lane >> 2;      // staging: edge row 0..15
    const int c    = lane & 3;       // staging: 4 lanes per row

    bf16_t* msg  = msg_all + w * TW * MSG_LD;   // [16][MSG_LD]
    bf16_t* hS   = msg;                          // [16][H_LD] overlay (h)
    bf16_t* mT   = msg;                          // [64][MT_LD] overlay (m transposed), 3072 B

    // ---- one-time: transpose W1,W2 into LDS (bf16) ----
    for (int i = t; i < IN_DIM * HID / 4; i += 256) {
        float4 v = ((const float4*)W1)[i];
        int k = i >> 4, j4 = (i & 15) * 4;      // W1[k][j4..j4+3]
        w1T[(j4 + 0) * W1_LD + k] = (bf16_t)v.x;
        w1T[(j4 + 1) * W1_LD + k] = (bf16_t)v.y;
        w1T[(j4 + 2) * W1_LD + k] = (bf16_t)v.z;
        w1T[(j4 + 3) * W1_LD + k] = (bf16_t)v.w;
    }
    for (int i = t; i < HID * ND / 4; i += 256) {
        float4 v = ((const float4*)W2)[i];
        int k = i >> 4, j4 = (i & 15) * 4;
        w2T[(j4 + 0) * W2_LD + k] = (bf16_t)v.x;
        w2T[(j4 + 1) * W2_LD + k] = (bf16_t)v.y;
        w2T[(j4 + 2) * W2_LD + k] = (bf16_t)v.z;
        w2T[(j4 + 3) * W2_LD + k] = (bf16_t)v.w;
    }
    float b1r[4], b2r[4];
    #pragma unroll
    for (int nt = 0; nt < 4; ++nt) {
        b1r[nt] = b1[col + 16 * nt];
        b2r[nt] = b2[col + 16 * nt];
    }
    __syncthreads();   // the only block barrier

    const int ntiles = NEDGE / TW;               // 100000
    const int wid = blockIdx.x * 4 + w;
    const int nw  = gridDim.x * 4;

    // ---- prefetch registers: this lane's share of one tile ----
    float4 xv0, xv1, xv2, xv3;   // x row chunks c, c+4, c+8, c+12
    float4 ev0, ev1;             // ea row chunks c*2, c*2+1
    int    dstv;                 // dst of edge eb+col (lanes 16..63 replicate)

    { // prologue: load first tile
        const int eb0 = wid * TW;
        int2 rec = pd[eb0 + e];
        dstv = pd[eb0 + col].y;
        const float4* xr = (const float4*)(x + (size_t)rec.y * ND);
        const float4* er = (const float4*)(edge_attr + (size_t)rec.x * ED);
        xv0 = xr[c]; xv1 = xr[c + 4]; xv2 = xr[c + 8]; xv3 = xr[c + 12];
        ev0 = er[c * 2]; ev1 = er[c * 2 + 1];
    }

    for (int tile = wid; tile < ntiles; tile += nw) {
        const int dcur = dstv;   // current tile's dsts (lane i<16 holds dst of row i)

        // ---- stage current registers into LDS (coalesced pattern) ----
        {
            bf16x4_t p;
            p[0] = (bf16_t)xv0.x; p[1] = (bf16_t)xv0.y; p[2] = (bf16_t)xv0.z; p[3] = (bf16_t)xv0.w;
            *(bf16x4_t*)&msg[e * MSG_LD + (c + 0) * 4] = p;
            p[0] = (bf16_t)xv1.x; p[1] = (bf16_t)xv1.y; p[2] = (bf16_t)xv1.z; p[3] = (bf16_t)xv1.w;
            *(bf16x4_t*)&msg[e * MSG_LD + (c + 4) * 4] = p;
            p[0] = (bf16_t)xv2.x; p[1] = (bf16_t)xv2.y; p[2] = (bf16_t)xv2.z; p[3] = (bf16_t)xv2.w;
            *(bf16x4_t*)&msg[e * MSG_LD + (c + 8) * 4] = p;
            p[0] = (bf16_t)xv3.x; p[1] = (bf16_t)xv3.y; p[2] = (bf16_t)xv3.z; p[3] = (bf16_t)xv3.w;
            *(bf16x4_t*)&msg[e * MSG_LD + (c + 12) * 4] = p;
            p[0] = (bf16_t)ev0.x; p[1] = (bf16_t)ev0.y; p[2] = (bf16_t)ev0.z; p[3] = (bf16_t)ev0.w;
            *(bf16x4_t*)&msg[e * MSG_LD + ND + (c * 2 + 0) * 4] = p;
            p[0] = (bf16_t)ev1.x; p[1] = (bf16_t)ev1.y; p[2] = (bf16_t)ev1.z; p[3] = (bf16_t)ev1.w;
            *(bf16x4_t*)&msg[e * MSG_LD + ND + (c * 2 + 1) * 4] = p;
        }

        // ---- issue next tile's loads (fly during GEMM+scatter below) ----
        if (tile + nw < ntiles) {
            const int eb1 = (tile + nw) * TW;
            int2 rec = pd[eb1 + e];
            dstv = pd[eb1 + col].y;
            const float4* xr = (const float4*)(x + (size_t)rec.y * ND);
            const float4* er = (const float4*)(edge_attr + (size_t)rec.x * ED);
            xv0 = xr[c]; xv1 = xr[c + 4]; xv2 = xr[c + 8]; xv3 = xr[c + 12];
            ev0 = er[c * 2]; ev1 = er[c * 2 + 1];
        }

        // ---- GEMM1: h[0..15][0..63] = relu(msg @ W1 + b1) ----
        const int ab = col * MSG_LD + kq * 8;
        bf16x8_t af0 = *(const bf16x8_t*)&msg[ab + 0 * 32];
        bf16x8_t af1 = *(const bf16x8_t*)&msg[ab + 1 * 32];
        bf16x8_t af2 = *(const bf16x8_t*)&msg[ab + 2 * 32];
        f32x4_t acc[4];
        #pragma unroll
        for (int nt = 0; nt < 4; ++nt) {
            const bf16_t* wrow = &w1T[(col + 16 * nt) * W1_LD + kq * 8];
            bf16x8_t f0 = *(const bf16x8_t*)(wrow + 0 * 32);
            bf16x8_t f1 = *(const bf16x8_t*)(wrow + 1 * 32);
            bf16x8_t f2 = *(const bf16x8_t*)(wrow + 2 * 32);
            acc[nt] = (f32x4_t){0.0f, 0.0f, 0.0f, 0.0f};
            acc[nt] = __builtin_amdgcn_mfma_f32_16x16x32_bf16(af0, f0, acc[nt], 0, 0, 0);
            acc[nt] = __builtin_amdgcn_mfma_f32_16x16x32_bf16(af1, f1, acc[nt], 0, 0, 0);
            acc[nt] = __builtin_amdgcn_mfma_f32_16x16x32_bf16(af2, f2, acc[nt], 0, 0, 0);
        }
        // epilogue: bias+relu -> hS (C/D: row = 4*kq + r, col = col + 16*nt)
        #pragma unroll
        for (int nt = 0; nt < 4; ++nt)
            #pragma unroll
            for (int r = 0; r < 4; ++r)
                hS[(4 * kq + r) * H_LD + col + 16 * nt] =
                    (bf16_t)fmaxf(acc[nt][r] + b1r[nt], 0.0f);

        // ---- GEMM2: m = relu(h @ W2 + b2) ----
        const int hb = col * H_LD + kq * 8;
        bf16x8_t ah0 = *(const bf16x8_t*)&hS[hb + 0 * 32];
        bf16x8_t ah1 = *(const bf16x8_t*)&hS[hb + 1 * 32];
        f32x4_t acc2[4];
        #pragma unroll
        for (int nt = 0; nt < 4; ++nt) {
            const bf16_t* wrow = &w2T[(col + 16 * nt) * W2_LD + kq * 8];
            bf16x8_t f0 = *(const bf16x8_t*)(wrow + 0 * 32);
            bf16x8_t f1 = *(const bf16x8_t*)(wrow + 1 * 32);
            acc2[nt] = (f32x4_t){0.0f, 0.0f, 0.0f, 0.0f};
            acc2[nt] = __builtin_amdgcn_mfma_f32_16x16x32_bf16(ah0, f0, acc2[nt], 0, 0, 0);
            acc2[nt] = __builtin_amdgcn_mfma_f32_16x16x32_bf16(ah1, f1, acc2[nt], 0, 0, 0);
        }
        // epilogue: bias+relu -> mT transposed: mT[col+16nt][4kq+r]
        // (h reads above already issued; in-order DS pipe -> overlay safe)
        #pragma unroll
        for (int nt = 0; nt < 4; ++nt)
            #pragma unroll
            for (int r = 0; r < 4; ++r)
                mT[(col + 16 * nt) * MT_LD + 4 * kq + r] =
                    (bf16_t)fmaxf(acc2[nt][r] + b2r[nt], 0.0f);

        // ---- scatter: lane reads its output column's 16 values as 2 x b128 ----
        {
            bf16x8_t v0 = *(const bf16x8_t*)&mT[lane * MT_LD + 0];
            bf16x8_t v1 = *(const bf16x8_t*)&mT[lane * MT_LD + 8];
            float mval[16];
            #pragma unroll
            for (int j = 0; j < 8; ++j) { mval[j] = (float)v0[j]; mval[8 + j] = (float)v1[j]; }

            // fixed 16-iteration run-merge; dsts via readlane (compile-time index)
            int cur = __builtin_amdgcn_readlane(dcur, 0);
            float s = 0.0f;
            #pragma unroll
            for (int r = 0; r < TW; ++r) {
                const int d = __builtin_amdgcn_readlane(dcur, r);   // SALU, uniform
                if (d != cur) {
                    atomicAdd(&out_sum[(size_t)cur * ND + lane], s);
                    s = 0.0f; cur = d;
                }
                s += mval[r];
            }
            atomicAdd(&out_sum[(size_t)cur * ND + lane], s);
        }
    }
}

// ---------------- K5: finalize out = sum/max(cnt,1) + x ----------------
__global__ void finalize_kernel(const float* __restrict__ x,
                                const int* __restrict__ cnt,
                                float* __restrict__ out)
{
    int i = blockIdx.x * blockDim.x + threadIdx.x;
    int stride = gridDim.x * blockDim.x;
    const int total4 = NODES * ND / 4;
    for (int idx = i; idx < total4; idx += stride) {
        const int n = idx / (ND / 4);
        const float inv = 1.0f / fmaxf((float)cnt[n], 1.0f);
        float4 s = ((const float4*)out)[idx];
        float4 xv = ((const float4*)x)[idx];
        float4 r;
        r.x = s.x * inv + xv.x;
        r.y = s.y * inv + xv.y;
        r.z = s.z * inv + xv.z;
        r.w = s.w * inv + xv.w;
        ((float4*)out)[idx] = r;
    }
}

extern "C" void kernel_launch(void* const* d_in, const int* in_sizes, int n_in,
                              void* d_out, int out_size, void* d_ws, size_t ws_size,
                              hipStream_t stream) {
    const float* x  = (const float*)d_in[0];
    const int*   ei = (const int*)d_in[1];     // int64 in reference -> int32 on device
    const float* ea = (const float*)d_in[2];
    const float* W1 = (const float*)d_in[3];
    const float* b1 = (const float*)d_in[4];
    const float* W2 = (const float*)d_in[5];
    const float* b2 = (const float*)d_in[6];
    float* out = (float*)d_out;

    // d_ws layout (ints): cnt[N] | cursor[N] | pd[2E] | bsum[256]
    int*  cnt    = (int*)d_ws;
    int*  cursor = cnt + NODES;
    int2* pd     = (int2*)(cursor + NODES);
    int*  bsum   = (int*)(pd + NEDGE);

    hipLaunchKernelGGL(zero_kernel, dim3(2048), dim3(256), 0, stream, out, cnt);
    hipLaunchKernelGGL(hist_kernel, dim3(2048), dim3(256), 0, stream, ei, cnt);
    hipLaunchKernelGGL(scan_sum_kernel, dim3(SCAN_NBLK), dim3(SCAN_B), 0, stream, cnt, bsum);
    hipLaunchKernelGGL(scan_top_kernel, dim3(1), dim3(SCAN_B), 0, stream, bsum);
    hipLaunchKernelGGL(scan_fill_kernel, dim3(SCAN_NBLK), dim3(SCAN_B), 0, stream, cnt, bsum, cursor);
    hipLaunchKernelGGL(bucket_kernel, dim3(2048), dim3(256), 0, stream, ei, cursor, pd);
    hipLaunchKernelGGL(edge_mlp_mfma, dim3(1024), dim3(256), 0, stream,
                       x, ea, W1, b1, W2, b2, pd, out);
    hipLaunchKernelGGL(finalize_kernel, dim3(1600), dim3(256), 0, stream, x, cnt, out);
}